// Round 5
// baseline (1324.052 us; speedup 1.0000x reference)
//
#include <hip/hip_runtime.h>
#include <math.h>

constexpr int NP = 100000, NA = 50000, NS = 5000;
constexpr int EPA = 600000, EAP = 600000, EPS = 200000, ESP = 200000;
// concatenated relation order: pa | ps | ap | sp   (dst spaces: A | S | P | P)
constexpr int ETOT = EPA + EPS + EAP + ESP;            // 1.6M
constexpr int NT   = NA + NS + NP + NP;                // 255000 global dst rows
constexpr int OFF_PS = EPA, OFF_AP = EPA + EPS, OFF_SP = EPA + EPS + EAP;
constexpr int ROW_PS = NA, ROW_AP = NA + NS, ROW_SP = NA + NS + NP;
constexpr int NBUCK = (ETOT + 4095) / 4096;            // 391 slot-space buckets

typedef short s16x8 __attribute__((ext_vector_type(8)));
typedef float f32x4 __attribute__((ext_vector_type(4)));
typedef unsigned short u16;

__device__ __forceinline__ float gelu_f(float x) {
  float x3 = x*x*x;
  return 0.5f*x*(1.0f + tanhf(0.7978845608028654f*(x + 0.044715f*x3)));
}
__device__ __forceinline__ u16 f2bf(float f) {
  unsigned u = __float_as_uint(f);
  u += 0x7fffu + ((u >> 16) & 1u);     // RNE
  return (u16)(u >> 16);
}
__device__ __forceinline__ float bf2f(u16 s) {
  return __uint_as_float((unsigned)s << 16);
}

// ---------------- encoder W fragment packing (K=256) ----------------
// Wp[((ks*8+cf)*64 + l)*8 + b] = bf16( W[ks*32 + (l>>4)*8 + b][cf*16 + (l&15)] )
__global__ void pack_w(const float* __restrict__ W, u16* __restrict__ Wp, int K) {
  int o = blockIdx.x*256 + threadIdx.x;
  if (o >= K*128) return;
  int b  = o & 7;
  int l  = (o >> 3) & 63;
  int cf = (o >> 9) & 7;
  int ks = o >> 12;
  int k   = ks*32 + (l >> 4)*8 + b;
  int col = cf*16 + (l & 15);
  Wp[o] = f2bf(W[k*128 + col]);
}

// ---------------- weight folding (f32, tiny) ----------------
// T0 = w0_pa @ w1_ap ; T1 = w0_ps @ w1_sp
__global__ __launch_bounds__(256) void fold_a(
    const float* __restrict__ A0, const float* __restrict__ B0,
    const float* __restrict__ A1, const float* __restrict__ B1,
    float* __restrict__ T)   // T[2][128*128]
{
  int o = blockIdx.x*256 + threadIdx.x;
  if (o >= 2*128*128) return;
  const float* A = (o < 128*128) ? A0 : A1;
  const float* B = (o < 128*128) ? B0 : B1;
  int p = o & (128*128-1);
  int r = p >> 7, c = p & 127;
  float acc = 0.f;
  #pragma unroll 4
  for (int k = 0; k < 128; ++k) acc = fmaf(A[r*128+k], B[k*128+c], acc);
  T[o] = acc;
}

// WFi[k*32 + which*16 + c] = (T_which @ out_w)[k][c]   -> interleaved [128][32]
__global__ __launch_bounds__(256) void fold_b(
    const float* __restrict__ T, const float* __restrict__ OW,
    float* __restrict__ WFi)
{
  int o = blockIdx.x*256 + threadIdx.x;
  if (o >= 2*128*16) return;
  int which = (o >= 128*16);
  const float* A = T + (size_t)which*128*128;
  int p = o & (128*16-1);
  int r = p >> 4, c = p & 15;
  float acc = 0.f;
  #pragma unroll 4
  for (int k = 0; k < 128; ++k) acc = fmaf(A[r*128+k], OW[k*16+c], acc);
  WFi[r*32 + which*16 + c] = acc;
}

// ---------------- fused encoder: yz = gelu(x_p @ Wenc + b) @ [Wao|Wso] ----------------
// block = 64 rows (4 waves x 16 rows); h staged in LDS (bf16), WF in LDS (f32).
__global__ __launch_bounds__(256) void enc_fused(
    const float* __restrict__ A, const u16* __restrict__ Wp,
    const float* __restrict__ bias, const float* __restrict__ WFi,
    float* __restrict__ YZ, int n)
{
  __shared__ u16  hl[64][132];     // padded: bank-friendly
  __shared__ float wf[128*32];
  const int tid = threadIdx.x;

  // stage folded head weights (4096 f32)
  #pragma unroll
  for (int i = 0; i < 4; ++i)
    ((float4*)wf)[tid + i*256] = ((const float4*)WFi)[tid + i*256];

  const int lane = tid & 63, wv = tid >> 6;
  const int rowbase = blockIdx.x*64 + wv*16;
  const int m  = lane & 15;
  const int kq = lane >> 4;

  f32x4 acc[8];
  #pragma unroll
  for (int j = 0; j < 8; ++j) acc[j] = (f32x4){0.f,0.f,0.f,0.f};

  const int r0 = rowbase + m;
  const bool v0 = r0 < n;
  const float* Arow = A + (size_t)r0*256 + kq*8;

  #pragma unroll
  for (int ks = 0; ks < 8; ++ks) {
    s16x8 a0 = {0,0,0,0,0,0,0,0};
    if (v0) {
      float4 f = *(const float4*)(Arow + ks*32);
      float4 g = *(const float4*)(Arow + ks*32 + 4);
      a0[0]=(short)f2bf(f.x); a0[1]=(short)f2bf(f.y); a0[2]=(short)f2bf(f.z); a0[3]=(short)f2bf(f.w);
      a0[4]=(short)f2bf(g.x); a0[5]=(short)f2bf(g.y); a0[6]=(short)f2bf(g.z); a0[7]=(short)f2bf(g.w);
    }
    const s16x8* Wf = (const s16x8*)Wp + (size_t)ks*512 + lane;
    #pragma unroll
    for (int cf = 0; cf < 8; ++cf)
      acc[cf] = __builtin_amdgcn_mfma_f32_16x16x32_bf16(a0, Wf[cf*64], acc[cf], 0, 0, 0);
  }

  // h -> LDS (bf16), D layout: col=lane&15, row-in-tile = kq*4 + r
  const int rlb = wv*16 + kq*4;
  #pragma unroll
  for (int cf = 0; cf < 8; ++cf) {
    const int col = cf*16 + m;
    const float bcol = bias[col];
    #pragma unroll
    for (int r = 0; r < 4; ++r)
      hl[rlb + r][col] = f2bf(gelu_f(acc[cf][r] + bcol));
  }
  __syncthreads();

  // yz[row][0..31] = h[row] @ wf ; thread t: row = t>>2, cols (t&3)*8 .. +7
  const int r = tid >> 2;
  const int cg = (tid & 3) * 8;
  const int grow = blockIdx.x*64 + r;
  if (grow >= n) return;
  float s[8];
  #pragma unroll
  for (int j = 0; j < 8; ++j) s[j] = 0.f;
  #pragma unroll 4
  for (int k = 0; k < 128; ++k) {
    const float hv = bf2f(hl[r][k]);
    const float* wk = wf + k*32 + cg;
    #pragma unroll
    for (int j = 0; j < 8; ++j) s[j] = fmaf(hv, wk[j], s[j]);
  }
  float* O = YZ + (size_t)grow*32 + cg;
  *(float4*)(O)   = make_float4(s[0], s[1], s[2], s[3]);
  *(float4*)(O+4) = make_float4(s[4], s[5], s[6], s[7]);
}

// ---------------- CSR build ----------------
__global__ void deg_count_all(
    const int* __restrict__ pa, const int* __restrict__ ps,
    const int* __restrict__ ap, const int* __restrict__ sp,
    int* __restrict__ deg)
{
  int e = blockIdx.x*256 + threadIdx.x;
  if (e >= ETOT) return;
  int d, off;
  if (e < OFF_PS)      { d = pa[e];          off = 0; }
  else if (e < OFF_AP) { d = ps[e - OFF_PS]; off = ROW_PS; }
  else if (e < OFF_SP) { d = ap[e - OFF_AP]; off = ROW_AP; }
  else                 { d = sp[e - OFF_SP]; off = ROW_SP; }
  atomicAdd(&deg[off + d], 1);
}

__global__ __launch_bounds__(256) void scan_partial(const int* __restrict__ in, int n,
                                                    int* __restrict__ part) {
  __shared__ int red[4];
  int base = blockIdx.x*4096;
  int sum = 0;
  for (int i = threadIdx.x; i < 4096; i += 256) {
    int idx = base + i;
    sum += (idx < n) ? in[idx] : 0;
  }
  #pragma unroll
  for (int off = 32; off; off >>= 1) sum += __shfl_down(sum, off, 64);
  if ((threadIdx.x & 63) == 0) red[threadIdx.x >> 6] = sum;
  __syncthreads();
  if (threadIdx.x == 0) part[blockIdx.x] = red[0]+red[1]+red[2]+red[3];
}

__global__ __launch_bounds__(256) void scan_chunk(const int* __restrict__ in, int n,
    const int* __restrict__ part, int* __restrict__ out)
{
  int off0 = 0;
  for (int i = 0; i < (int)blockIdx.x; ++i) off0 += part[i];
  const int base = blockIdx.x*4096 + threadIdx.x*16;
  int loc[16]; int s = 0;
  #pragma unroll
  for (int j = 0; j < 16; ++j) {
    int idx = base + j;
    int v = (idx < n) ? in[idx] : 0;
    loc[j] = s; s += v;
  }
  __shared__ int ts[256];
  ts[threadIdx.x] = s; __syncthreads();
  for (int off = 1; off < 256; off <<= 1) {
    int t = (threadIdx.x >= off) ? ts[threadIdx.x - off] : 0;
    __syncthreads();
    ts[threadIdx.x] += t;
    __syncthreads();
  }
  int excl = off0 + ts[threadIdx.x] - s;
  #pragma unroll
  for (int j = 0; j < 16; ++j) {
    int idx = base + j;
    if (idx < n) out[idx] = excl + loc[j];
    if (idx == n-1) out[n] = excl + loc[j] + in[idx];
  }
}

// phase 1: route (slot, src) into slot-space buckets (sequential writes per bucket)
__global__ void fill_p1(
    const int* __restrict__ pa_s, const int* __restrict__ pa_d,
    const int* __restrict__ ps_s, const int* __restrict__ ps_d,
    const int* __restrict__ ap_s, const int* __restrict__ ap_d,
    const int* __restrict__ sp_s, const int* __restrict__ sp_d,
    const int* __restrict__ rp, int* __restrict__ cur,
    int* __restrict__ bcur, uint2* __restrict__ buf)
{
  int e = blockIdx.x*256 + threadIdx.x;
  if (e >= ETOT) return;
  int s, d, off;
  if (e < OFF_PS)      { s = pa_s[e];          d = pa_d[e];          off = 0; }
  else if (e < OFF_AP) { s = ps_s[e - OFF_PS]; d = ps_d[e - OFF_PS]; off = ROW_PS; }
  else if (e < OFF_SP) { s = ap_s[e - OFF_AP]; d = ap_d[e - OFF_AP]; off = ROW_AP; }
  else                 { s = sp_s[e - OFF_SP]; d = sp_d[e - OFF_SP]; off = ROW_SP; }
  int grow = off + d;
  int slot = rp[grow] + atomicAdd(&cur[grow], 1);
  int b = slot >> 12;
  int pos = atomicAdd(&bcur[b], 1);
  buf[((size_t)b << 12) + pos] = make_uint2((unsigned)slot, (unsigned)s);
}

// phase 2: one block per bucket; deposit via LDS, write ci fully coalesced
__global__ __launch_bounds__(256) void fill_p2(const uint2* __restrict__ buf,
    const int* __restrict__ bcur, int* __restrict__ ci)
{
  __shared__ int lds[4096];
  const int b = blockIdx.x;
  const int nb = bcur[b];
  const uint2* B = buf + ((size_t)b << 12);
  for (int i = threadIdx.x; i < nb; i += 256) {
    uint2 u = B[i];
    lds[u.x & 4095] = (int)u.y;
  }
  __syncthreads();
  const int base = b << 12;
  for (int i = threadIdx.x; i < 4096; i += 256) {
    int slot = base + i;
    if (slot < ETOT) ci[slot] = lds[i];
  }
}

// ---------------- 16-wide gathers ----------------
// authors (rows<NA): mean of yz[src][0..15]; subjects: mean of yz[src][16..31]
__global__ __launch_bounds__(256) void gather16(const float* __restrict__ yz,
    const int* __restrict__ rp, const int* __restrict__ ci,
    float* __restrict__ m16, int n)
{
  int t = blockIdx.x*256 + threadIdx.x;
  int row = t >> 4, lane = t & 15;
  if (row >= n) return;
  int beg = rp[row], end = rp[row+1];
  int off = (row < NA ? 0 : 16) + lane;
  float a = 0.f, b = 0.f;
  int e = beg;
  for (; e + 1 < end; e += 2) {
    a += yz[(size_t)ci[e]  *32 + off];
    b += yz[(size_t)ci[e+1]*32 + off];
  }
  if (e < end) a += yz[(size_t)ci[e]*32 + off];
  int d = end - beg;
  m16[(size_t)row*16 + lane] = (a + b) / (float)(d > 0 ? d : 1);
}

// papers: out = mean_ap(m16_a) + mean_sp(m16_s) + out_b
__global__ __launch_bounds__(256) void gather2_16(
    const float* __restrict__ f1, const int* __restrict__ rp1,
    const float* __restrict__ f2, const int* __restrict__ rp2,
    const int* __restrict__ ci, const float* __restrict__ ob,
    float* __restrict__ O, int n)
{
  int t = blockIdx.x*256 + threadIdx.x;
  int row = t >> 4, lane = t & 15;
  if (row >= n) return;

  float s1 = 0.f, s1b = 0.f;
  {
    int beg = rp1[row], end = rp1[row+1];
    int e = beg;
    for (; e + 1 < end; e += 2) {
      s1  += f1[(size_t)ci[e]  *16 + lane];
      s1b += f1[(size_t)ci[e+1]*16 + lane];
    }
    if (e < end) s1 += f1[(size_t)ci[e]*16 + lane];
    int d = end - beg;
    s1 = (s1 + s1b) / (float)(d > 0 ? d : 1);
  }
  float s2 = 0.f, s2b = 0.f;
  {
    int beg = rp2[row], end = rp2[row+1];
    int e = beg;
    for (; e + 1 < end; e += 2) {
      s2  += f2[(size_t)ci[e]  *16 + lane];
      s2b += f2[(size_t)ci[e+1]*16 + lane];
    }
    if (e < end) s2 += f2[(size_t)ci[e]*16 + lane];
    int d = end - beg;
    s2 = (s2 + s2b) / (float)(d > 0 ? d : 1);
  }
  O[(size_t)row*16 + lane] = s1 + s2 + ob[lane];
}

extern "C" void kernel_launch(void* const* d_in, const int* in_sizes, int n_in,
                              void* d_out, int out_size, void* d_ws, size_t ws_size,
                              hipStream_t stream)
{
  const float* x_p = (const float*)d_in[0];
  const int* pa_src=(const int*)d_in[3]; const int* pa_dst=(const int*)d_in[4];
  const int* ap_src=(const int*)d_in[5]; const int* ap_dst=(const int*)d_in[6];
  const int* ps_src=(const int*)d_in[7]; const int* ps_dst=(const int*)d_in[8];
  const int* sp_src=(const int*)d_in[9]; const int* sp_dst=(const int*)d_in[10];
  const float* ewp=(const float*)d_in[11]; const float* ebp=(const float*)d_in[12];
  const float* w0_pa=(const float*)d_in[17];
  const float* w0_ps=(const float*)d_in[19];
  const float* w1_ap=(const float*)d_in[22];
  const float* w1_sp=(const float*)d_in[24];
  const float* out_w=(const float*)d_in[25]; const float* out_b=(const float*)d_in[26];
  float* out = (float*)d_out;

  // ---- workspace layout (~26 MB; R4 established ws_size >= ~50 MB) ----
  char* wp = (char*)d_ws;
  auto alloc = [&](size_t bytes) { char* p = wp; wp += (bytes + 255) & ~(size_t)255; return p; };
  // buf (CSR phase-1) and yz (encoder output) overlay: disjoint lifetimes
  char*  bufyz = alloc((size_t)NBUCK*4096*8);            // 12.82 MB
  uint2* buf   = (uint2*)bufyz;
  float* yz    = (float*)bufyz;                          // NP*32*4 = 12.8 MB
  int*   ci    = (int*)alloc((size_t)ETOT*4);            // 6.4 MB
  float* m16   = (float*)alloc((size_t)(NA+NS)*16*4);    // 3.52 MB
  u16*   wpk   = (u16*)alloc((size_t)256*128*2);
  float* Tfold = (float*)alloc((size_t)2*128*128*4);
  float* WFi   = (float*)alloc((size_t)128*32*4);
  int*   deg   = (int*)alloc((size_t)(2*NT + NBUCK)*4);  // deg | cursor | bcur (one memset)
  int*   cursor= deg + NT;
  int*   bcur  = cursor + NT;
  int*   rpG   = (int*)alloc((size_t)(NT+1)*4);
  int*   part  = (int*)alloc((size_t)64*4);

  // ---- weight prep ----
  pack_w<<<(256*128+255)/256,256,0,stream>>>(ewp, wpk, 256);
  fold_a<<<(2*128*128+255)/256,256,0,stream>>>(w0_pa, w1_ap, w0_ps, w1_sp, Tfold);
  fold_b<<<(2*128*16+255)/256,256,0,stream>>>(Tfold, out_w, WFi);

  // ---- CSR build ----
  hipMemsetAsync(deg, 0, (size_t)(2*NT + NBUCK)*4, stream);
  deg_count_all<<<(ETOT+255)/256,256,0,stream>>>(pa_dst, ps_dst, ap_dst, sp_dst, deg);
  int nch = (NT + 4095)/4096;
  scan_partial<<<nch,256,0,stream>>>(deg, NT, part);
  scan_chunk  <<<nch,256,0,stream>>>(deg, NT, part, rpG);
  fill_p1<<<(ETOT+255)/256,256,0,stream>>>(pa_src, pa_dst, ps_src, ps_dst,
                                           ap_src, ap_dst, sp_src, sp_dst,
                                           rpG, cursor, bcur, buf);
  fill_p2<<<NBUCK,256,0,stream>>>(buf, bcur, ci);

  // ---- fused encoder + folded head (overwrites buf with yz) ----
  enc_fused<<<(NP+63)/64,256,0,stream>>>(x_p, wpk, ebp, WFi, yz, NP);

  // ---- author+subject 16-wide aggregation ----
  gather16<<<(((size_t)(NA+NS)*16)+255)/256,256,0,stream>>>(yz, rpG, ci, m16, NA+NS);

  // ---- final paper aggregation + bias -> d_out ----
  gather2_16<<<(((size_t)NP*16)+255)/256,256,0,stream>>>(
      m16, rpG + ROW_AP,
      m16 + (size_t)NA*16, rpG + ROW_SP,
      ci, out_b, out, NP);
}

// Round 6
// 280.644 us; speedup vs baseline: 4.7179x; 4.7179x over previous
//
#include <hip/hip_runtime.h>
#include <math.h>

constexpr int NP = 100000, NA = 50000, NS = 5000;
constexpr int EPA = 600000, EAP = 600000, EPS = 200000, ESP = 200000;
// concatenated relation order: pa | ps | ap | sp   (dst spaces: A | S | P | P)
constexpr int ETOT = EPA + EPS + EAP + ESP;            // 1.6M
constexpr int NT   = NA + NS + NP + NP;                // 255000 global dst rows
constexpr int OFF_PS = EPA, OFF_AP = EPA + EPS, OFF_SP = EPA + EPS + EAP;
constexpr int ROW_PS = NA, ROW_AP = NA + NS, ROW_SP = NA + NS + NP;

constexpr int NB_FOLD = 2;
constexpr int NB_PACK = (256*128)/256;      // 128
constexpr int NB_DEG  = (ETOT+255)/256;     // 6250
constexpr int NB_ENC  = (NP+63)/64;         // 1563
constexpr int NB_K3   = NB_ENC*5;           // 7815: b%5==4 -> enc, else fill (6252 >= 6250)

typedef short s16x8 __attribute__((ext_vector_type(8)));
typedef float f32x4 __attribute__((ext_vector_type(4)));
typedef unsigned short u16;

__device__ __forceinline__ float gelu_f(float x) {
  float x3 = x*x*x;
  return 0.5f*x*(1.0f + tanhf(0.7978845608028654f*(x + 0.044715f*x3)));
}
__device__ __forceinline__ u16 f2bf(float f) {
  unsigned u = __float_as_uint(f);
  u += 0x7fffu + ((u >> 16) & 1u);     // RNE
  return (u16)(u >> 16);
}
__device__ __forceinline__ float bf2f(u16 s) {
  return __uint_as_float((unsigned)s << 16);
}

// ================= K0: fold-chain | pack_w | deg histogram =================
__global__ __launch_bounds__(256) void prep_all(
    const float* __restrict__ w0_pa, const float* __restrict__ w1_ap,
    const float* __restrict__ w0_ps, const float* __restrict__ w1_sp,
    const float* __restrict__ out_w, float* __restrict__ WFi,
    const float* __restrict__ ewp, u16* __restrict__ wpk,
    const int* __restrict__ pa_d, const int* __restrict__ ps_d,
    const int* __restrict__ ap_d, const int* __restrict__ sp_d,
    int* __restrict__ deg)
{
  __shared__ float U[128*16];
  const int b = blockIdx.x, tid = threadIdx.x;

  if (b < NB_FOLD) {
    // Wao = w0_pa @ (w1_ap @ out_w)  (b=0 -> cols 0..15), likewise ps/sp (b=1 -> 16..31)
    const float* w0 = (b == 0) ? w0_pa : w0_ps;
    const float* w1 = (b == 0) ? w1_ap : w1_sp;
    #pragma unroll
    for (int j = 0; j < 8; ++j) {
      int idx = j*256 + tid;          // 2048 = 128x16
      int r = idx >> 4, c = idx & 15;
      float acc = 0.f;
      #pragma unroll 4
      for (int k = 0; k < 128; ++k) acc = fmaf(w1[r*128+k], out_w[k*16+c], acc);
      U[idx] = acc;
    }
    __syncthreads();
    #pragma unroll
    for (int j = 0; j < 8; ++j) {
      int idx = j*256 + tid;
      int r = idx >> 4, c = idx & 15;
      float acc = 0.f;
      #pragma unroll 4
      for (int k = 0; k < 128; ++k) acc = fmaf(w0[r*128+k], U[k*16+c], acc);
      WFi[r*32 + b*16 + c] = acc;     // interleaved [128][32]
    }
    return;
  }
  if (b < NB_FOLD + NB_PACK) {
    // Wp[((ks*8+cf)*64 + l)*8 + bb] = bf16( W[ks*32 + (l>>4)*8 + bb][cf*16 + (l&15)] )
    int o = (b - NB_FOLD)*256 + tid;
    int bb = o & 7;
    int l  = (o >> 3) & 63;
    int cf = (o >> 9) & 7;
    int ks = o >> 12;
    int k   = ks*32 + (l >> 4)*8 + bb;
    int col = cf*16 + (l & 15);
    wpk[o] = f2bf(ewp[k*128 + col]);
    return;
  }
  // degree histogram over concatenated dst space
  int e = (b - NB_FOLD - NB_PACK)*256 + tid;
  if (e >= ETOT) return;
  int d, off;
  if (e < OFF_PS)      { d = pa_d[e];          off = 0; }
  else if (e < OFF_AP) { d = ps_d[e - OFF_PS]; off = ROW_PS; }
  else if (e < OFF_SP) { d = ap_d[e - OFF_AP]; off = ROW_AP; }
  else                 { d = sp_d[e - OFF_SP]; off = ROW_SP; }
  atomicAdd(&deg[off + d], 1);
}

// ================= scans =================
__global__ __launch_bounds__(256) void scan_partial(const int* __restrict__ in, int n,
                                                    int* __restrict__ part) {
  __shared__ int red[4];
  int base = blockIdx.x*4096;
  int sum = 0;
  for (int i = threadIdx.x; i < 4096; i += 256) {
    int idx = base + i;
    sum += (idx < n) ? in[idx] : 0;
  }
  #pragma unroll
  for (int off = 32; off; off >>= 1) sum += __shfl_down(sum, off, 64);
  if ((threadIdx.x & 63) == 0) red[threadIdx.x >> 6] = sum;
  __syncthreads();
  if (threadIdx.x == 0) part[blockIdx.x] = red[0]+red[1]+red[2]+red[3];
}

__global__ __launch_bounds__(256) void scan_chunk(const int* __restrict__ in, int n,
    const int* __restrict__ part, int* __restrict__ out)
{
  int off0 = 0;
  for (int i = 0; i < (int)blockIdx.x; ++i) off0 += part[i];
  const int base = blockIdx.x*4096 + threadIdx.x*16;
  int loc[16]; int s = 0;
  #pragma unroll
  for (int j = 0; j < 16; ++j) {
    int idx = base + j;
    int v = (idx < n) ? in[idx] : 0;
    loc[j] = s; s += v;
  }
  __shared__ int ts[256];
  ts[threadIdx.x] = s; __syncthreads();
  for (int off = 1; off < 256; off <<= 1) {
    int t = (threadIdx.x >= off) ? ts[threadIdx.x - off] : 0;
    __syncthreads();
    ts[threadIdx.x] += t;
    __syncthreads();
  }
  int excl = off0 + ts[threadIdx.x] - s;
  #pragma unroll
  for (int j = 0; j < 16; ++j) {
    int idx = base + j;
    if (idx < n) out[idx] = excl + loc[j];
    if (idx == n-1) out[n] = excl + loc[j] + in[idx];
  }
}

// ================= K3: fused encoder || CSR fill =================
// b%5==4: encoder block (yz = gelu(x_p @ Wenc + b) @ [Wao|Wso]);  else: CSR fill block.
__global__ __launch_bounds__(256) void enc_fill(
    const float* __restrict__ A, const u16* __restrict__ Wp,
    const float* __restrict__ bias, const float* __restrict__ WFi,
    float* __restrict__ YZ,
    const int* __restrict__ pa_s, const int* __restrict__ pa_d,
    const int* __restrict__ ps_s, const int* __restrict__ ps_d,
    const int* __restrict__ ap_s, const int* __restrict__ ap_d,
    const int* __restrict__ sp_s, const int* __restrict__ sp_d,
    const int* __restrict__ rp, int* __restrict__ cur, int* __restrict__ ci)
{
  __shared__ u16   hl[64][132];
  __shared__ float wf[128*32];
  const int b = blockIdx.x;
  const int tid = threadIdx.x;

  if ((b % 5) != 4) {
    // ---- CSR fill role (R4-proven: cursor atomics over 255K rows) ----
    int fb = b - b/5;
    int e = fb*256 + tid;
    if (e >= ETOT) return;
    int s, d, off;
    if (e < OFF_PS)      { s = pa_s[e];          d = pa_d[e];          off = 0; }
    else if (e < OFF_AP) { s = ps_s[e - OFF_PS]; d = ps_d[e - OFF_PS]; off = ROW_PS; }
    else if (e < OFF_SP) { s = ap_s[e - OFF_AP]; d = ap_d[e - OFF_AP]; off = ROW_AP; }
    else                 { s = sp_s[e - OFF_SP]; d = sp_d[e - OFF_SP]; off = ROW_SP; }
    int grow = off + d;
    int p = atomicAdd(&cur[grow], 1);
    ci[rp[grow] + p] = s;
    return;
  }

  // ---- encoder role ----
  const int eb = b / 5;

  #pragma unroll
  for (int i = 0; i < 4; ++i)
    ((float4*)wf)[tid + i*256] = ((const float4*)WFi)[tid + i*256];

  const int lane = tid & 63, wv = tid >> 6;
  const int rowbase = eb*64 + wv*16;
  const int m  = lane & 15;
  const int kq = lane >> 4;

  f32x4 acc[8];
  #pragma unroll
  for (int j = 0; j < 8; ++j) acc[j] = (f32x4){0.f,0.f,0.f,0.f};

  const int r0 = rowbase + m;
  const bool v0 = r0 < NP;
  const float* Arow = A + (size_t)r0*256 + kq*8;

  #pragma unroll
  for (int ks = 0; ks < 8; ++ks) {
    s16x8 a0 = {0,0,0,0,0,0,0,0};
    if (v0) {
      float4 f = *(const float4*)(Arow + ks*32);
      float4 g = *(const float4*)(Arow + ks*32 + 4);
      a0[0]=(short)f2bf(f.x); a0[1]=(short)f2bf(f.y); a0[2]=(short)f2bf(f.z); a0[3]=(short)f2bf(f.w);
      a0[4]=(short)f2bf(g.x); a0[5]=(short)f2bf(g.y); a0[6]=(short)f2bf(g.z); a0[7]=(short)f2bf(g.w);
    }
    const s16x8* Wf = (const s16x8*)Wp + (size_t)ks*512 + lane;
    #pragma unroll
    for (int cf = 0; cf < 8; ++cf)
      acc[cf] = __builtin_amdgcn_mfma_f32_16x16x32_bf16(a0, Wf[cf*64], acc[cf], 0, 0, 0);
  }

  // h -> LDS (bf16); D layout: col = lane&15, row-in-tile = kq*4 + r
  const int rlb = wv*16 + kq*4;
  #pragma unroll
  for (int cf = 0; cf < 8; ++cf) {
    const int col = cf*16 + m;
    const float bcol = bias[col];
    #pragma unroll
    for (int r = 0; r < 4; ++r)
      hl[rlb + r][col] = f2bf(gelu_f(acc[cf][r] + bcol));
  }
  __syncthreads();

  // yz[row][0..31] = h[row] @ wf ; thread t: row = t>>2, cols (t&3)*8..+7
  const int r = tid >> 2;
  const int cg = (tid & 3) * 8;
  const int grow = eb*64 + r;
  if (grow >= NP) return;
  float s[8];
  #pragma unroll
  for (int j = 0; j < 8; ++j) s[j] = 0.f;
  #pragma unroll 4
  for (int k = 0; k < 128; ++k) {
    const float hv = bf2f(hl[r][k]);
    const float* wk = wf + k*32 + cg;
    #pragma unroll
    for (int j = 0; j < 8; ++j) s[j] = fmaf(hv, wk[j], s[j]);
  }
  float* O = YZ + (size_t)grow*32 + cg;
  *(float4*)(O)   = make_float4(s[0], s[1], s[2], s[3]);
  *(float4*)(O+4) = make_float4(s[4], s[5], s[6], s[7]);
}

// ================= 16-wide gathers =================
// authors (rows<NA): mean of yz[src][0..15]; subjects: mean of yz[src][16..31]
__global__ __launch_bounds__(256) void gather16(const float* __restrict__ yz,
    const int* __restrict__ rp, const int* __restrict__ ci,
    float* __restrict__ m16, int n)
{
  int t = blockIdx.x*256 + threadIdx.x;
  int row = t >> 4, lane = t & 15;
  if (row >= n) return;
  int beg = rp[row], end = rp[row+1];
  int off = (row < NA ? 0 : 16) + lane;
  float a = 0.f, b = 0.f;
  int e = beg;
  for (; e + 1 < end; e += 2) {
    a += yz[(size_t)ci[e]  *32 + off];
    b += yz[(size_t)ci[e+1]*32 + off];
  }
  if (e < end) a += yz[(size_t)ci[e]*32 + off];
  int d = end - beg;
  m16[(size_t)row*16 + lane] = (a + b) / (float)(d > 0 ? d : 1);
}

// papers: out = mean_ap(m16_a) + mean_sp(m16_s) + out_b
__global__ __launch_bounds__(256) void gather2_16(
    const float* __restrict__ f1, const int* __restrict__ rp1,
    const float* __restrict__ f2, const int* __restrict__ rp2,
    const int* __restrict__ ci, const float* __restrict__ ob,
    float* __restrict__ O, int n)
{
  int t = blockIdx.x*256 + threadIdx.x;
  int row = t >> 4, lane = t & 15;
  if (row >= n) return;

  float s1 = 0.f, s1b = 0.f;
  {
    int beg = rp1[row], end = rp1[row+1];
    int e = beg;
    for (; e + 1 < end; e += 2) {
      s1  += f1[(size_t)ci[e]  *16 + lane];
      s1b += f1[(size_t)ci[e+1]*16 + lane];
    }
    if (e < end) s1 += f1[(size_t)ci[e]*16 + lane];
    int d = end - beg;
    s1 = (s1 + s1b) / (float)(d > 0 ? d : 1);
  }
  float s2 = 0.f, s2b = 0.f;
  {
    int beg = rp2[row], end = rp2[row+1];
    int e = beg;
    for (; e + 1 < end; e += 2) {
      s2  += f2[(size_t)ci[e]  *16 + lane];
      s2b += f2[(size_t)ci[e+1]*16 + lane];
    }
    if (e < end) s2 += f2[(size_t)ci[e]*16 + lane];
    int d = end - beg;
    s2 = (s2 + s2b) / (float)(d > 0 ? d : 1);
  }
  O[(size_t)row*16 + lane] = s1 + s2 + ob[lane];
}

extern "C" void kernel_launch(void* const* d_in, const int* in_sizes, int n_in,
                              void* d_out, int out_size, void* d_ws, size_t ws_size,
                              hipStream_t stream)
{
  const float* x_p = (const float*)d_in[0];
  const int* pa_src=(const int*)d_in[3]; const int* pa_dst=(const int*)d_in[4];
  const int* ap_src=(const int*)d_in[5]; const int* ap_dst=(const int*)d_in[6];
  const int* ps_src=(const int*)d_in[7]; const int* ps_dst=(const int*)d_in[8];
  const int* sp_src=(const int*)d_in[9]; const int* sp_dst=(const int*)d_in[10];
  const float* ewp=(const float*)d_in[11]; const float* ebp=(const float*)d_in[12];
  const float* w0_pa=(const float*)d_in[17];
  const float* w0_ps=(const float*)d_in[19];
  const float* w1_ap=(const float*)d_in[22];
  const float* w1_sp=(const float*)d_in[24];
  const float* out_w=(const float*)d_in[25]; const float* out_b=(const float*)d_in[26];
  float* out = (float*)d_out;

  // ---- workspace layout (~25 MB; R5 proved >=26 MB available) ----
  char* wp = (char*)d_ws;
  auto alloc = [&](size_t bytes) { char* p = wp; wp += (bytes + 255) & ~(size_t)255; return p; };
  float* yz    = (float*)alloc((size_t)NP*32*4);         // 12.8 MB
  int*   ci    = (int*)alloc((size_t)ETOT*4);            // 6.4 MB
  float* m16   = (float*)alloc((size_t)(NA+NS)*16*4);    // 3.52 MB
  u16*   wpk   = (u16*)alloc((size_t)256*128*2);
  float* WFi   = (float*)alloc((size_t)128*32*4);
  int*   deg   = (int*)alloc((size_t)2*NT*4);            // deg | cursor (one memset)
  int*   cursor= deg + NT;
  int*   rpG   = (int*)alloc((size_t)(NT+1)*4);
  int*   part  = (int*)alloc((size_t)64*4);

  // ---- K0: deg histogram + weight pack + folded head weights ----
  hipMemsetAsync(deg, 0, (size_t)2*NT*4, stream);
  prep_all<<<NB_FOLD+NB_PACK+NB_DEG,256,0,stream>>>(
      w0_pa, w1_ap, w0_ps, w1_sp, out_w, WFi, ewp, wpk,
      pa_dst, ps_dst, ap_dst, sp_dst, deg);

  // ---- scans -> rowptr ----
  int nch = (NT + 4095)/4096;   // 63
  scan_partial<<<nch,256,0,stream>>>(deg, NT, part);
  scan_chunk  <<<nch,256,0,stream>>>(deg, NT, part, rpG);

  // ---- K3: encoder || CSR fill (co-grid) ----
  enc_fill<<<NB_K3,256,0,stream>>>(
      x_p, wpk, ebp, WFi, yz,
      pa_src, pa_dst, ps_src, ps_dst, ap_src, ap_dst, sp_src, sp_dst,
      rpG, cursor, ci);

  // ---- author+subject 16-wide aggregation ----
  gather16<<<(((size_t)(NA+NS)*16)+255)/256,256,0,stream>>>(yz, rpG, ci, m16, NA+NS);

  // ---- final paper aggregation + bias -> d_out ----
  gather2_16<<<(((size_t)NP*16)+255)/256,256,0,stream>>>(
      m16, rpG + ROW_AP,
      m16 + (size_t)NA*16, rpG + ROW_SP,
      ci, out_b, out, NP);
}

// Round 7
// 263.706 us; speedup vs baseline: 5.0209x; 1.0642x over previous
//
#include <hip/hip_runtime.h>
#include <math.h>

constexpr int NP = 100000, NA = 50000, NS = 5000;
constexpr int EPA = 600000, EAP = 600000, EPS = 200000, ESP = 200000;
// concatenated relation order: pa | ps | ap | sp   (dst spaces: A | S | P | P)
constexpr int ETOT = EPA + EPS + EAP + ESP;            // 1.6M
constexpr int NT   = NA + NS + NP + NP;                // 255000 global dst rows
constexpr int OFF_PS = EPA, OFF_AP = EPA + EPS, OFF_SP = EPA + EPS + EAP;
constexpr int ROW_PS = NA, ROW_AP = NA + NS, ROW_SP = NA + NS + NP;

constexpr int NB_PACK = (256*128)/256;          // 128 pack blocks
constexpr int NB_HIST = (ETOT + 1023)/1024;     // 1563 (4 edges/thread)
constexpr int NB_ENC  = (NP + 63)/64;           // 1563
constexpr int NB_FILL = (ETOT + 1023)/1024;     // 1563

typedef short s16x8 __attribute__((ext_vector_type(8)));
typedef float f32x4 __attribute__((ext_vector_type(4)));
typedef unsigned short u16;

__device__ __forceinline__ float gelu_f(float x) {
  float x3 = x*x*x;
  return 0.5f*x*(1.0f + tanhf(0.7978845608028654f*(x + 0.044715f*x3)));
}
__device__ __forceinline__ u16 f2bf(float f) {
  unsigned u = __float_as_uint(f);
  u += 0x7fffu + ((u >> 16) & 1u);     // RNE
  return (u16)(u >> 16);
}
__device__ __forceinline__ float bf2f(u16 s) {
  return __uint_as_float((unsigned)s << 16);
}

// ================= K0: folded head weights (LDS-staged) + encoder W pack =================
// b<2: fold role.  WFi[r*32 + b*16 + c] = (w0 @ (w1 @ out_w))[r][c]
// b>=2: pack role. Wp[((ks*8+cf)*64+l)*8+bb] = bf16(ewp[(ks*32+(l>>4)*8+bb)*128 + cf*16+(l&15)])
__global__ __launch_bounds__(256) void fold_pack(
    const float* __restrict__ w0_pa, const float* __restrict__ w1_ap,
    const float* __restrict__ w0_ps, const float* __restrict__ w1_sp,
    const float* __restrict__ out_w, float* __restrict__ WFi,
    const float* __restrict__ ewp, u16* __restrict__ wpk)
{
  __shared__ float Wst[64*132];    // 33.8KB, stride-132 (bank-spread)
  __shared__ float OW[128*16];     // 8KB
  __shared__ float U[128*16];      // 8KB
  const int b = blockIdx.x, tid = threadIdx.x;

  if (b >= 2) {
    int o = (b - 2)*256 + tid;
    int bb = o & 7;
    int l  = (o >> 3) & 63;
    int cf = (o >> 9) & 7;
    int ks = o >> 12;
    wpk[o] = f2bf(ewp[(ks*32 + (l>>4)*8 + bb)*128 + cf*16 + (l & 15)]);
    return;
  }

  const float* w0 = (b == 0) ? w0_pa : w0_ps;
  const float* w1 = (b == 0) ? w1_ap : w1_sp;
  for (int i = tid; i < 512; i += 256) ((float4*)OW)[i] = ((const float4*)out_w)[i];

  // U = w1 @ OW  (two 64-row halves staged in LDS)
  for (int half = 0; half < 2; ++half) {
    __syncthreads();
    for (int i = tid; i < 64*32; i += 256) {
      int row = i >> 5, q = i & 31;
      float4 v = ((const float4*)(w1 + (size_t)(half*64 + row)*128))[q];
      *(float4*)&Wst[row*132 + q*4] = v;
    }
    __syncthreads();
    #pragma unroll
    for (int i = 0; i < 4; ++i) {
      int idx = tid + 256*i;          // 0..1023
      int r = idx >> 4, c = idx & 15;
      float acc = 0.f;
      #pragma unroll 8
      for (int k = 0; k < 128; ++k) acc = fmaf(Wst[r*132+k], OW[k*16+c], acc);
      U[(half*64 + r)*16 + c] = acc;
    }
  }
  // WF = w0 @ U
  for (int half = 0; half < 2; ++half) {
    __syncthreads();
    for (int i = tid; i < 64*32; i += 256) {
      int row = i >> 5, q = i & 31;
      float4 v = ((const float4*)(w0 + (size_t)(half*64 + row)*128))[q];
      *(float4*)&Wst[row*132 + q*4] = v;
    }
    __syncthreads();
    #pragma unroll
    for (int i = 0; i < 4; ++i) {
      int idx = tid + 256*i;
      int r = idx >> 4, c = idx & 15;
      float acc = 0.f;
      #pragma unroll 8
      for (int k = 0; k < 128; ++k) acc = fmaf(Wst[r*132+k], U[k*16+c], acc);
      WFi[(half*64 + r)*32 + b*16 + c] = acc;
    }
  }
}

// ================= K1: degree histogram (4 edges/thread, no LDS) =================
__global__ void hist4(
    const int* __restrict__ pa_d, const int* __restrict__ ps_d,
    const int* __restrict__ ap_d, const int* __restrict__ sp_d,
    int* __restrict__ deg)
{
  int e = (blockIdx.x*256 + threadIdx.x)*4;
  if (e >= ETOT) return;
  const int* dsts; int off;
  if (e < OFF_PS)      { dsts = pa_d;          off = 0; }
  else if (e < OFF_AP) { dsts = ps_d - OFF_PS; off = ROW_PS; }
  else if (e < OFF_SP) { dsts = ap_d - OFF_AP; off = ROW_AP; }
  else                 { dsts = sp_d - OFF_SP; off = ROW_SP; }
  int4 d4 = *(const int4*)(dsts + e);
  atomicAdd(&deg[off + d4.x], 1);
  atomicAdd(&deg[off + d4.y], 1);
  atomicAdd(&deg[off + d4.z], 1);
  atomicAdd(&deg[off + d4.w], 1);
}

// ================= scans =================
__global__ __launch_bounds__(256) void scan_partial(const int* __restrict__ in, int n,
                                                    int* __restrict__ part) {
  __shared__ int red[4];
  int base = blockIdx.x*4096;
  int sum = 0;
  for (int i = threadIdx.x; i < 4096; i += 256) {
    int idx = base + i;
    sum += (idx < n) ? in[idx] : 0;
  }
  #pragma unroll
  for (int off = 32; off; off >>= 1) sum += __shfl_down(sum, off, 64);
  if ((threadIdx.x & 63) == 0) red[threadIdx.x >> 6] = sum;
  __syncthreads();
  if (threadIdx.x == 0) part[blockIdx.x] = red[0]+red[1]+red[2]+red[3];
}

__global__ __launch_bounds__(256) void scan_chunk(const int* __restrict__ in, int n,
    const int* __restrict__ part, int* __restrict__ out)
{
  int off0 = 0;
  for (int i = 0; i < (int)blockIdx.x; ++i) off0 += part[i];
  const int base = blockIdx.x*4096 + threadIdx.x*16;
  int loc[16]; int s = 0;
  #pragma unroll
  for (int j = 0; j < 16; ++j) {
    int idx = base + j;
    int v = (idx < n) ? in[idx] : 0;
    loc[j] = s; s += v;
  }
  __shared__ int ts[256];
  ts[threadIdx.x] = s; __syncthreads();
  for (int off = 1; off < 256; off <<= 1) {
    int t = (threadIdx.x >= off) ? ts[threadIdx.x - off] : 0;
    __syncthreads();
    ts[threadIdx.x] += t;
    __syncthreads();
  }
  int excl = off0 + ts[threadIdx.x] - s;
  #pragma unroll
  for (int j = 0; j < 16; ++j) {
    int idx = base + j;
    if (idx < n) out[idx] = excl + loc[j];
    if (idx == n-1) out[n] = excl + loc[j] + in[idx];
  }
}

// ================= K4: fused encoder || CSR fill (4 edges/thread) =================
// b odd: encoder block; b even: fill block.
__global__ __launch_bounds__(256) void enc_fill(
    const float* __restrict__ A, const u16* __restrict__ Wp,
    const float* __restrict__ bias, const float* __restrict__ WFi,
    float* __restrict__ YZ,
    const int* __restrict__ pa_s, const int* __restrict__ pa_d,
    const int* __restrict__ ps_s, const int* __restrict__ ps_d,
    const int* __restrict__ ap_s, const int* __restrict__ ap_d,
    const int* __restrict__ sp_s, const int* __restrict__ sp_d,
    const int* __restrict__ rp, int* __restrict__ cur, int* __restrict__ ci)
{
  __shared__ u16   hl[64][132];
  __shared__ float wf[128*32];
  const int b = blockIdx.x;
  const int tid = threadIdx.x;

  if (!(b & 1)) {
    // ---- CSR fill role: 4 independent atomic->store chains per thread ----
    int e = ((b >> 1)*256 + tid)*4;
    if (e >= ETOT) return;
    const int *srcs, *dsts; int off;
    if (e < OFF_PS)      { srcs = pa_s;          dsts = pa_d;          off = 0; }
    else if (e < OFF_AP) { srcs = ps_s - OFF_PS; dsts = ps_d - OFF_PS; off = ROW_PS; }
    else if (e < OFF_SP) { srcs = ap_s - OFF_AP; dsts = ap_d - OFF_AP; off = ROW_AP; }
    else                 { srcs = sp_s - OFF_SP; dsts = sp_d - OFF_SP; off = ROW_SP; }
    int4 s4 = *(const int4*)(srcs + e);
    int4 d4 = *(const int4*)(dsts + e);
    int g0 = off + d4.x, g1 = off + d4.y, g2 = off + d4.z, g3 = off + d4.w;
    int p0 = atomicAdd(&cur[g0], 1);
    int p1 = atomicAdd(&cur[g1], 1);
    int p2 = atomicAdd(&cur[g2], 1);
    int p3 = atomicAdd(&cur[g3], 1);
    ci[rp[g0] + p0] = s4.x;
    ci[rp[g1] + p1] = s4.y;
    ci[rp[g2] + p2] = s4.z;
    ci[rp[g3] + p3] = s4.w;
    return;
  }

  // ---- encoder role: yz = gelu(x_p @ Wenc + b) @ [Wao|Wso] ----
  const int eb = b >> 1;

  #pragma unroll
  for (int i = 0; i < 4; ++i)
    ((float4*)wf)[tid + i*256] = ((const float4*)WFi)[tid + i*256];

  const int lane = tid & 63, wv = tid >> 6;
  const int rowbase = eb*64 + wv*16;
  const int m  = lane & 15;
  const int kq = lane >> 4;

  f32x4 acc[8];
  #pragma unroll
  for (int j = 0; j < 8; ++j) acc[j] = (f32x4){0.f,0.f,0.f,0.f};

  const int r0 = rowbase + m;
  const bool v0 = r0 < NP;
  const float* Arow = A + (size_t)r0*256 + kq*8;

  #pragma unroll
  for (int ks = 0; ks < 8; ++ks) {
    s16x8 a0 = {0,0,0,0,0,0,0,0};
    if (v0) {
      float4 f = *(const float4*)(Arow + ks*32);
      float4 g = *(const float4*)(Arow + ks*32 + 4);
      a0[0]=(short)f2bf(f.x); a0[1]=(short)f2bf(f.y); a0[2]=(short)f2bf(f.z); a0[3]=(short)f2bf(f.w);
      a0[4]=(short)f2bf(g.x); a0[5]=(short)f2bf(g.y); a0[6]=(short)f2bf(g.z); a0[7]=(short)f2bf(g.w);
    }
    const s16x8* Wf = (const s16x8*)Wp + (size_t)ks*512 + lane;
    #pragma unroll
    for (int cf = 0; cf < 8; ++cf)
      acc[cf] = __builtin_amdgcn_mfma_f32_16x16x32_bf16(a0, Wf[cf*64], acc[cf], 0, 0, 0);
  }

  // h -> LDS (bf16); D layout: col = lane&15, row-in-tile = kq*4 + r
  const int rlb = wv*16 + kq*4;
  #pragma unroll
  for (int cf = 0; cf < 8; ++cf) {
    const int col = cf*16 + m;
    const float bcol = bias[col];
    #pragma unroll
    for (int r = 0; r < 4; ++r)
      hl[rlb + r][col] = f2bf(gelu_f(acc[cf][r] + bcol));
  }
  __syncthreads();

  // yz[row][0..31] = h[row] @ wf ; thread t: row = t>>2, cols (t&3)*8..+7
  const int r = tid >> 2;
  const int cg = (tid & 3) * 8;
  const int grow = eb*64 + r;
  if (grow >= NP) return;
  float s[8];
  #pragma unroll
  for (int j = 0; j < 8; ++j) s[j] = 0.f;
  #pragma unroll 4
  for (int k = 0; k < 128; ++k) {
    const float hv = bf2f(hl[r][k]);
    const float* wk = wf + k*32 + cg;
    #pragma unroll
    for (int j = 0; j < 8; ++j) s[j] = fmaf(hv, wk[j], s[j]);
  }
  float* O = YZ + (size_t)grow*32 + cg;
  *(float4*)(O)   = make_float4(s[0], s[1], s[2], s[3]);
  *(float4*)(O+4) = make_float4(s[4], s[5], s[6], s[7]);
}

// ================= 16-wide gathers =================
__global__ __launch_bounds__(256) void gather16(const float* __restrict__ yz,
    const int* __restrict__ rp, const int* __restrict__ ci,
    float* __restrict__ m16, int n)
{
  int t = blockIdx.x*256 + threadIdx.x;
  int row = t >> 4, lane = t & 15;
  if (row >= n) return;
  int beg = rp[row], end = rp[row+1];
  int off = (row < NA ? 0 : 16) + lane;
  float a = 0.f, b = 0.f;
  int e = beg;
  for (; e + 1 < end; e += 2) {
    a += yz[(size_t)ci[e]  *32 + off];
    b += yz[(size_t)ci[e+1]*32 + off];
  }
  if (e < end) a += yz[(size_t)ci[e]*32 + off];
  int d = end - beg;
  m16[(size_t)row*16 + lane] = (a + b) / (float)(d > 0 ? d : 1);
}

__global__ __launch_bounds__(256) void gather2_16(
    const float* __restrict__ f1, const int* __restrict__ rp1,
    const float* __restrict__ f2, const int* __restrict__ rp2,
    const int* __restrict__ ci, const float* __restrict__ ob,
    float* __restrict__ O, int n)
{
  int t = blockIdx.x*256 + threadIdx.x;
  int row = t >> 4, lane = t & 15;
  if (row >= n) return;

  float s1 = 0.f, s1b = 0.f;
  {
    int beg = rp1[row], end = rp1[row+1];
    int e = beg;
    for (; e + 1 < end; e += 2) {
      s1  += f1[(size_t)ci[e]  *16 + lane];
      s1b += f1[(size_t)ci[e+1]*16 + lane];
    }
    if (e < end) s1 += f1[(size_t)ci[e]*16 + lane];
    int d = end - beg;
    s1 = (s1 + s1b) / (float)(d > 0 ? d : 1);
  }
  float s2 = 0.f, s2b = 0.f;
  {
    int beg = rp2[row], end = rp2[row+1];
    int e = beg;
    for (; e + 1 < end; e += 2) {
      s2  += f2[(size_t)ci[e]  *16 + lane];
      s2b += f2[(size_t)ci[e+1]*16 + lane];
    }
    if (e < end) s2 += f2[(size_t)ci[e]*16 + lane];
    int d = end - beg;
    s2 = (s2 + s2b) / (float)(d > 0 ? d : 1);
  }
  O[(size_t)row*16 + lane] = s1 + s2 + ob[lane];
}

extern "C" void kernel_launch(void* const* d_in, const int* in_sizes, int n_in,
                              void* d_out, int out_size, void* d_ws, size_t ws_size,
                              hipStream_t stream)
{
  const float* x_p = (const float*)d_in[0];
  const int* pa_src=(const int*)d_in[3]; const int* pa_dst=(const int*)d_in[4];
  const int* ap_src=(const int*)d_in[5]; const int* ap_dst=(const int*)d_in[6];
  const int* ps_src=(const int*)d_in[7]; const int* ps_dst=(const int*)d_in[8];
  const int* sp_src=(const int*)d_in[9]; const int* sp_dst=(const int*)d_in[10];
  const float* ewp=(const float*)d_in[11]; const float* ebp=(const float*)d_in[12];
  const float* w0_pa=(const float*)d_in[17];
  const float* w0_ps=(const float*)d_in[19];
  const float* w1_ap=(const float*)d_in[22];
  const float* w1_sp=(const float*)d_in[24];
  const float* out_w=(const float*)d_in[25]; const float* out_b=(const float*)d_in[26];
  float* out = (float*)d_out;

  // ---- workspace layout (~25 MB) ----
  char* wp = (char*)d_ws;
  auto alloc = [&](size_t bytes) { char* p = wp; wp += (bytes + 255) & ~(size_t)255; return p; };
  float* yz    = (float*)alloc((size_t)NP*32*4);         // 12.8 MB
  int*   ci    = (int*)alloc((size_t)ETOT*4);            // 6.4 MB
  float* m16   = (float*)alloc((size_t)(NA+NS)*16*4);    // 3.52 MB
  u16*   wpk   = (u16*)alloc((size_t)256*128*2);
  float* WFi   = (float*)alloc((size_t)128*32*4);
  int*   deg   = (int*)alloc((size_t)2*NT*4);            // deg | cursor (one memset)
  int*   cursor= deg + NT;
  int*   rpG   = (int*)alloc((size_t)(NT+1)*4);
  int*   part  = (int*)alloc((size_t)64*4);

  // ---- K0: folded head weights + encoder pack ----
  hipMemsetAsync(deg, 0, (size_t)2*NT*4, stream);
  fold_pack<<<2+NB_PACK,256,0,stream>>>(w0_pa, w1_ap, w0_ps, w1_sp, out_w, WFi, ewp, wpk);

  // ---- K1: degree histogram ----
  hist4<<<NB_HIST,256,0,stream>>>(pa_dst, ps_dst, ap_dst, sp_dst, deg);

  // ---- K2/K3: scans -> rowptr ----
  int nch = (NT + 4095)/4096;   // 63
  scan_partial<<<nch,256,0,stream>>>(deg, NT, part);
  scan_chunk  <<<nch,256,0,stream>>>(deg, NT, part, rpG);

  // ---- K4: encoder || CSR fill (co-grid) ----
  enc_fill<<<NB_ENC + NB_FILL,256,0,stream>>>(
      x_p, wpk, ebp, WFi, yz,
      pa_src, pa_dst, ps_src, ps_dst, ap_src, ap_dst, sp_src, sp_dst,
      rpG, cursor, ci);

  // ---- K5: author+subject 16-wide aggregation ----
  gather16<<<(((size_t)(NA+NS)*16)+255)/256,256,0,stream>>>(yz, rpG, ci, m16, NA+NS);

  // ---- K6: final paper aggregation + bias -> d_out ----
  gather2_16<<<(((size_t)NP*16)+255)/256,256,0,stream>>>(
      m16, rpG + ROW_AP,
      m16 + (size_t)NA*16, rpG + ROW_SP,
      ci, out_b, out, NP);
}